// Round 4
// baseline (665.995 us; speedup 1.0000x reference)
//
#include <hip/hip_runtime.h>

// SMPL forward: B=512, V=6890, NB=10, NJ=24, 9 extra joints. Output fp32 (B, 6923, 3).
// R4 structure: 4 dispatches — memset, precompute(atomic), joints(shfl chain, zeroes
// extra slots), lbs(fused skinning + extra-joint atomic reduction, LDS-staged A).

#define BATCH 512
#define NV 6890
#define NBD 10
#define NJ 24
#define NEXTRA 9
#define NOUT (NV + NJ + NEXTRA)   // 6923
#define VBLK ((NV + 255) / 256)   // 27
#define BPB 4                     // batches per lbs block (sequential)

__constant__ int c_par[NJ] = {-1,0,0,0,1,2,3,4,5,6,7,8,9,9,9,12,13,14,16,17,18,19,20,21};
__constant__ int c_lvl[NJ] = { 0,1,1,1,2,2,2,3,3,3,4,4,4, 4, 4, 5, 5, 5, 6, 6, 7, 7, 8, 8};

// ---------------------------------------------------------------------------
// Kernel A: batch-independent regressor precompute (unchanged — verified).
// jtjs[j][0:3] = Jreg@v_template ; jtjs[j][3+k*10+l] = Jreg@shapedirs
// ---------------------------------------------------------------------------
__global__ __launch_bounds__(256) void precompute_kernel(
    const float* __restrict__ jreg,
    const float* __restrict__ smpl_t,
    const float* __restrict__ smil_t,
    const float* __restrict__ sdirs,
    const float* __restrict__ msc,
    float* __restrict__ jtjs)
{
    const int j = blockIdx.y;
    const int v = blockIdx.x * 256 + threadIdx.x;
    const float s = msc[0];

    float acc[33];
#pragma unroll
    for (int i = 0; i < 33; ++i) acc[i] = 0.f;

    if (v < NV) {
        const float w = jreg[j * NV + v];
#pragma unroll
        for (int k = 0; k < 3; ++k) {
            float vt = s * smpl_t[v * 3 + k] + (1.f - s) * smil_t[v * 3 + k];
            acc[k] = w * vt;
        }
        const float2* sd2 = (const float2*)(sdirs + (size_t)v * 30);
#pragma unroll
        for (int i = 0; i < 15; ++i) {
            float2 x = sd2[i];
            acc[3 + 2 * i]     = w * x.x;
            acc[3 + 2 * i + 1] = w * x.y;
        }
    }

#pragma unroll
    for (int i = 0; i < 33; ++i) {
        float x = acc[i];
        for (int off = 32; off; off >>= 1) x += __shfl_xor(x, off, 64);
        acc[i] = x;
    }

    __shared__ float red[4][33];
    const int lane = threadIdx.x & 63, wv = threadIdx.x >> 6;
    if (lane == 0) {
#pragma unroll
        for (int i = 0; i < 33; ++i) red[wv][i] = acc[i];
    }
    __syncthreads();
    if (threadIdx.x < 33) {
        float sum = red[0][threadIdx.x] + red[1][threadIdx.x]
                  + red[2][threadIdx.x] + red[3][threadIdx.x];
        atomicAdd(&jtjs[j * 33 + threadIdx.x], sum);
    }
}

// ---------------------------------------------------------------------------
// Kernel B: per-batch joints — barrier-free. One wave per batch; chain compose
// via __shfl from the parent lane (levels 1..8). Lanes 0..23 own joints.
// Writes A[b,j] to wsA, posed joints (+transl) to out, and ZEROES the 27
// extra-joint slots (lbs atomically accumulates into them afterwards).
// ---------------------------------------------------------------------------
__global__ __launch_bounds__(64) void joints_kernel(
    const float* __restrict__ betas,
    const float* __restrict__ body_pose,
    const float* __restrict__ glob_or,
    const float* __restrict__ transl,
    const float* __restrict__ jtjs,
    float* __restrict__ wsA,
    float* __restrict__ out)
{
    const int b = blockIdx.x;
    const int j = threadIdx.x;          // 0..63, joints on 0..23
    const bool act = j < NJ;

    const float beta0 = betas[b * (NBD + 1)];   // uniform → s_load

    float sJ0 = 0.f, sJ1 = 0.f, sJ2 = 0.f;
    float M[12];
#pragma unroll
    for (int k = 0; k < 12; ++k) M[k] = 0.f;

    if (act) {
        float a0 = jtjs[j * 33 + 0];
        float a1 = jtjs[j * 33 + 1];
        float a2 = jtjs[j * 33 + 2];
#pragma unroll
        for (int l = 0; l < NBD; ++l) {
            const float bl = betas[b * (NBD + 1) + 1 + l];   // uniform
            a0 = fmaf(bl, jtjs[j * 33 + 3 + 0 * 10 + l], a0);
            a1 = fmaf(bl, jtjs[j * 33 + 3 + 1 * 10 + l], a1);
            a2 = fmaf(bl, jtjs[j * 33 + 3 + 2 * 10 + l], a2);
        }
        sJ0 = a0 * beta0; sJ1 = a1 * beta0; sJ2 = a2 * beta0;

        float rx, ry, rz;
        if (j == 0) {
            rx = glob_or[b * 3 + 0]; ry = glob_or[b * 3 + 1]; rz = glob_or[b * 3 + 2];
        } else {
            rx = body_pose[b * 69 + (j - 1) * 3 + 0];
            ry = body_pose[b * 69 + (j - 1) * 3 + 1];
            rz = body_pose[b * 69 + (j - 1) * 3 + 2];
        }
        float ex = rx + 1e-8f, ey = ry + 1e-8f, ez = rz + 1e-8f;
        float ang = sqrtf(ex * ex + ey * ey + ez * ez);
        float inv = 1.f / ang;
        float ax = rx * inv, ay = ry * inv, az = rz * inv;
        float c = cosf(ang), s = sinf(ang), t = 1.f - c;
        M[0]  = 1.f + t * (-(ay * ay + az * az));
        M[1]  = -s * az + t * (ax * ay);
        M[2]  =  s * ay + t * (ax * az);
        M[4]  =  s * az + t * (ax * ay);
        M[5]  = 1.f + t * (-(ax * ax + az * az));
        M[6]  = -s * ax + t * (ay * az);
        M[8]  = -s * ay + t * (ax * az);
        M[9]  =  s * ax + t * (ay * az);
        M[10] = 1.f + t * (-(ax * ax + ay * ay));
    }

    const int p = act ? c_par[j] : 0;
    const int psel = (p >= 0) ? p : 0;
    const int lvl = act ? c_lvl[j] : 0;

    // rel_joints: subtract parent's J
    {
        float pj0 = __shfl(sJ0, psel);
        float pj1 = __shfl(sJ1, psel);
        float pj2 = __shfl(sJ2, psel);
        if (act) {
            M[3]  = sJ0 - ((p >= 0) ? pj0 : 0.f);
            M[7]  = sJ1 - ((p >= 0) ? pj1 : 0.f);
            M[11] = sJ2 - ((p >= 0) ? pj2 : 0.f);
        }
    }

    // chain compose, level-parallel via shfl; C starts as M (root final at level 0)
    float C[12];
#pragma unroll
    for (int k = 0; k < 12; ++k) C[k] = M[k];
#pragma unroll
    for (int level = 1; level <= 8; ++level) {
        float P[12];
#pragma unroll
        for (int k = 0; k < 12; ++k) P[k] = __shfl(C[k], psel);
        if (act && lvl == level) {
#pragma unroll
            for (int r = 0; r < 3; ++r) {
#pragma unroll
                for (int col = 0; col < 4; ++col) {
                    float acc = (col == 3) ? P[r * 4 + 3] : 0.f;
#pragma unroll
                    for (int q = 0; q < 3; ++q)
                        acc = fmaf(P[r * 4 + q], M[q * 4 + col], acc);
                    C[r * 4 + col] = acc;
                }
            }
        }
    }

    if (act) {
        const float c0 = C[3], c1 = C[7], c2 = C[11];
        float A3  = c0 - (C[0] * sJ0 + C[1] * sJ1 + C[2]  * sJ2);
        float A7  = c1 - (C[4] * sJ0 + C[5] * sJ1 + C[6]  * sJ2);
        float A11 = c2 - (C[8] * sJ0 + C[9] * sJ1 + C[10] * sJ2);
        float* Aout = wsA + ((size_t)b * NJ + j) * 12;
        Aout[0] = C[0]; Aout[1] = C[1]; Aout[2]  = C[2];  Aout[3]  = A3;
        Aout[4] = C[4]; Aout[5] = C[5]; Aout[6]  = C[6];  Aout[7]  = A7;
        Aout[8] = C[8]; Aout[9] = C[9]; Aout[10] = C[10]; Aout[11] = A11;

        const float tx = transl[b * 3 + 0], ty = transl[b * 3 + 1], tz = transl[b * 3 + 2];
        const size_t o = ((size_t)b * NOUT + NV + j) * 3;
        out[o + 0] = c0 + tx; out[o + 1] = c1 + ty; out[o + 2] = c2 + tz;
    }
    // zero the extra-joint accumulation slots (consumed by lbs atomics)
    if (j < 27) out[((size_t)b * NOUT + NV + NJ) * 3 + j] = 0.f;
}

// ---------------------------------------------------------------------------
// Kernel C: fused LBS skinning + extra-joint regression.
// grid (27, BATCH/BPB), block 256. A[4 batches] staged in LDS (4.6 KB) →
// ds_read broadcasts replace chunked s_load waits. Per batch: skin verts,
// write out, accumulate 27 extra-joint partial sums, wave butterfly all-reduce,
// lane0 atomicAdd into out (slots pre-zeroed by joints_kernel).
// Batch loop NOT unrolled (R2 lesson: register explosion → scratch spill).
// ---------------------------------------------------------------------------
__global__ __launch_bounds__(256, 4) void lbs_kernel(
    const float* __restrict__ betas,
    const float* __restrict__ transl,
    const float* __restrict__ msc,
    const float* __restrict__ smpl_t,
    const float* __restrict__ smil_t,
    const float* __restrict__ sdirs,
    const float* __restrict__ lbsw,
    const float* __restrict__ jre,
    const float* __restrict__ wsA,
    float* __restrict__ out)
{
    __shared__ float sA[BPB * NJ * 12];   // 1152 floats

    const int tid = threadIdx.x;
    const int v = blockIdx.x * 256 + tid;
    const bool valid = v < NV;
    const int vc = valid ? v : NV - 1;
    const int b0 = blockIdx.y * BPB;
    const float s = msc[0];

    // stage A for 4 batches (coalesced)
    for (int i = tid; i < BPB * NJ * 12; i += 256)
        sA[i] = wsA[(size_t)b0 * NJ * 12 + i];

    // per-vertex, batch-independent data → registers
    float vt[3];
#pragma unroll
    for (int k = 0; k < 3; ++k)
        vt[k] = s * smpl_t[vc * 3 + k] + (1.f - s) * smil_t[vc * 3 + k];

    float sd[30];
    {
        const float2* sd2 = (const float2*)(sdirs + (size_t)vc * 30);
#pragma unroll
        for (int i = 0; i < 15; ++i) { float2 x = sd2[i]; sd[2 * i] = x.x; sd[2 * i + 1] = x.y; }
    }
    float w[NJ];
    {
        const float4* w4 = (const float4*)(lbsw + (size_t)vc * NJ);
#pragma unroll
        for (int i = 0; i < 6; ++i) {
            float4 x = w4[i];
            w[4 * i] = x.x; w[4 * i + 1] = x.y; w[4 * i + 2] = x.z; w[4 * i + 3] = x.w;
        }
    }
    float je[NEXTRA];
#pragma unroll
    for (int e = 0; e < NEXTRA; ++e)
        je[e] = valid ? jre[e * NV + vc] : 0.f;   // 0 ⇒ invalid lanes contribute nothing

    __syncthreads();

#pragma unroll 1
    for (int bb = 0; bb < BPB; ++bb) {
        const int b = b0 + bb;
        const float* __restrict__ Bb = betas + b * (NBD + 1);   // uniform → s_load
        const float* Ab = sA + bb * NJ * 12;

        // v_shaped
        float vs[3];
#pragma unroll
        for (int k = 0; k < 3; ++k) {
            float a = vt[k];
#pragma unroll
            for (int l = 0; l < NBD; ++l) a = fmaf(Bb[1 + l], sd[k * 10 + l], a);
            vs[k] = a * Bb[0];
        }

        // T = sum_j w_j * A_j — LDS broadcast reads, 12 independent FMA chains
        float T[12];
#pragma unroll
        for (int k = 0; k < 12; ++k) T[k] = 0.f;
#pragma unroll
        for (int jj = 0; jj < NJ; ++jj) {
            const float ww = w[jj];
#pragma unroll
            for (int k = 0; k < 12; ++k) T[k] = fmaf(ww, Ab[jj * 12 + k], T[k]);
        }

        const float tx = transl[b * 3 + 0], ty = transl[b * 3 + 1], tz = transl[b * 3 + 2];
        const float ox = fmaf(T[0], vs[0], fmaf(T[1], vs[1], fmaf(T[2],  vs[2], T[3])))  + tx;
        const float oy = fmaf(T[4], vs[0], fmaf(T[5], vs[1], fmaf(T[6],  vs[2], T[7])))  + ty;
        const float oz = fmaf(T[8], vs[0], fmaf(T[9], vs[1], fmaf(T[10], vs[2], T[11]))) + tz;

        if (valid) {
            const size_t o = ((size_t)b * NOUT + v) * 3;
            out[o + 0] = ox; out[o + 1] = oy; out[o + 2] = oz;
        }

        // extra joints: acc[e*3+c] = sum_v jre[e,v] * vert[c]
        float acc[27];
#pragma unroll
        for (int e = 0; e < NEXTRA; ++e) {
            acc[e * 3 + 0] = je[e] * ox;
            acc[e * 3 + 1] = je[e] * oy;
            acc[e * 3 + 2] = je[e] * oz;
        }
#pragma unroll
        for (int i = 0; i < 27; ++i) {
            float x = acc[i];
            for (int off = 32; off; off >>= 1) x += __shfl_xor(x, off, 64);
            acc[i] = x;
        }
        if ((tid & 63) == 0) {
            float* dst = out + ((size_t)b * NOUT + NV + NJ) * 3;
#pragma unroll
            for (int i = 0; i < 27; ++i) atomicAdd(&dst[i], acc[i]);
        }
    }
}

// ---------------------------------------------------------------------------
extern "C" void kernel_launch(void* const* d_in, const int* in_sizes, int n_in,
                              void* d_out, int out_size, void* d_ws, size_t ws_size,
                              hipStream_t stream) {
    const float* betas     = (const float*)d_in[0];
    const float* body_pose = (const float*)d_in[1];
    const float* glob_or   = (const float*)d_in[2];
    const float* transl    = (const float*)d_in[3];
    const float* msc       = (const float*)d_in[4];
    const float* smpl_t    = (const float*)d_in[5];
    const float* smil_t    = (const float*)d_in[6];
    const float* sdirs     = (const float*)d_in[7];
    const float* jreg      = (const float*)d_in[8];
    const float* lbsw      = (const float*)d_in[9];
    const float* jre       = (const float*)d_in[10];

    float* out  = (float*)d_out;
    float* ws   = (float*)d_ws;
    float* jtjs = ws;            // 24*33 = 792 floats
    float* wsA  = ws + 792;      // 512*24*12 = 147456 floats

    hipMemsetAsync(jtjs, 0, NJ * 33 * sizeof(float), stream);

    dim3 gA(VBLK, NJ);
    precompute_kernel<<<gA, 256, 0, stream>>>(jreg, smpl_t, smil_t, sdirs, msc, jtjs);

    joints_kernel<<<BATCH, 64, 0, stream>>>(betas, body_pose, glob_or, transl, jtjs, wsA, out);

    dim3 gC(VBLK, BATCH / BPB);
    lbs_kernel<<<gC, 256, 0, stream>>>(betas, transl, msc, smpl_t, smil_t, sdirs,
                                       lbsw, jre, wsA, out);
}

// Round 5
// 567.277 us; speedup vs baseline: 1.1740x; 1.1740x over previous
//
#include <hip/hip_runtime.h>

// SMPL forward: B=512, V=6890, NB=10, NJ=24, 9 extra joints. Output fp32 (B, 6923, 3).
// R5 structure: memset → precompute(jtjs) → q_kernel(Q) → joints(A + posed + EXTRA
// joints via Q algebra) → lbs (pure skinning, LDS-staged A). No atomics on out.

#define BATCH 512
#define NV 6890
#define NBD 10
#define NJ 24
#define NEXTRA 9
#define NOUT (NV + NJ + NEXTRA)   // 6923
#define VBLK ((NV + 255) / 256)   // 27
#define BPB 4                     // batches per lbs block (sequential)
#define QSTR 37                   // Q row: smpl[3], smil[3], sd[30], w[1]

__constant__ int c_par[NJ] = {-1,0,0,0,1,2,3,4,5,6,7,8,9,9,9,12,13,14,16,17,18,19,20,21};
__constant__ int c_lvl[NJ] = { 0,1,1,1,2,2,2,3,3,3,4,4,4, 4, 4, 5, 5, 5, 6, 6, 7, 7, 8, 8};

// ---------------------------------------------------------------------------
// Kernel A: batch-independent joint-regressor precompute (unchanged — verified).
// jtjs[j][0:3] = Jreg@v_template ; jtjs[j][3+k*10+l] = Jreg@shapedirs
// ---------------------------------------------------------------------------
__global__ __launch_bounds__(256) void precompute_kernel(
    const float* __restrict__ jreg,
    const float* __restrict__ smpl_t,
    const float* __restrict__ smil_t,
    const float* __restrict__ sdirs,
    const float* __restrict__ msc,
    float* __restrict__ jtjs)
{
    const int j = blockIdx.y;
    const int v = blockIdx.x * 256 + threadIdx.x;
    const float s = msc[0];

    float acc[33];
#pragma unroll
    for (int i = 0; i < 33; ++i) acc[i] = 0.f;

    if (v < NV) {
        const float w = jreg[j * NV + v];
#pragma unroll
        for (int k = 0; k < 3; ++k) {
            float vt = s * smpl_t[v * 3 + k] + (1.f - s) * smil_t[v * 3 + k];
            acc[k] = w * vt;
        }
        const float2* sd2 = (const float2*)(sdirs + (size_t)v * 30);
#pragma unroll
        for (int i = 0; i < 15; ++i) {
            float2 x = sd2[i];
            acc[3 + 2 * i]     = w * x.x;
            acc[3 + 2 * i + 1] = w * x.y;
        }
    }

#pragma unroll
    for (int i = 0; i < 33; ++i) {
        float x = acc[i];
        for (int off = 32; off; off >>= 1) x += __shfl_xor(x, off, 64);
        acc[i] = x;
    }

    __shared__ float red[4][33];
    const int lane = threadIdx.x & 63, wv = threadIdx.x >> 6;
    if (lane == 0) {
#pragma unroll
        for (int i = 0; i < 33; ++i) red[wv][i] = acc[i];
    }
    __syncthreads();
    if (threadIdx.x < 33) {
        float sum = red[0][threadIdx.x] + red[1][threadIdx.x]
                  + red[2][threadIdx.x] + red[3][threadIdx.x];
        atomicAdd(&jtjs[j * 33 + threadIdx.x], sum);
    }
}

// ---------------------------------------------------------------------------
// Kernel A2: extra-joint regressor precompute (batch-independent).
// Q[(e*NJ+j)*37 + m]: m=0..2 Σ jre·w·smpl_k ; 3..5 Σ jre·w·smil_k ;
//                     6+k*10+l Σ jre·w·sd[k,l] ; 36 Σ jre·w.
// grid (NEXTRA, NJ) = 216 blocks, block 256, one block owns full V-reduction.
// ---------------------------------------------------------------------------
__global__ __launch_bounds__(256) void q_kernel(
    const float* __restrict__ jre,
    const float* __restrict__ lbsw,
    const float* __restrict__ smpl_t,
    const float* __restrict__ smil_t,
    const float* __restrict__ sdirs,
    float* __restrict__ Q)
{
    const int e = blockIdx.x;
    const int j = blockIdx.y;

    float acc[QSTR];
#pragma unroll
    for (int i = 0; i < QSTR; ++i) acc[i] = 0.f;

    for (int v = threadIdx.x; v < NV; v += 256) {
        const float jw = jre[e * NV + v] * lbsw[(size_t)v * NJ + j];
        acc[36] += jw;
#pragma unroll
        for (int k = 0; k < 3; ++k) {
            acc[k]     = fmaf(jw, smpl_t[v * 3 + k], acc[k]);
            acc[3 + k] = fmaf(jw, smil_t[v * 3 + k], acc[3 + k]);
        }
        const float2* sd2 = (const float2*)(sdirs + (size_t)v * 30);
#pragma unroll
        for (int i = 0; i < 15; ++i) {
            float2 x = sd2[i];
            acc[6 + 2 * i]     = fmaf(jw, x.x, acc[6 + 2 * i]);
            acc[6 + 2 * i + 1] = fmaf(jw, x.y, acc[6 + 2 * i + 1]);
        }
    }

#pragma unroll
    for (int i = 0; i < QSTR; ++i) {
        float x = acc[i];
        for (int off = 32; off; off >>= 1) x += __shfl_xor(x, off, 64);
        acc[i] = x;
    }
    __shared__ float red[4][QSTR];
    const int lane = threadIdx.x & 63, wv = threadIdx.x >> 6;
    if (lane == 0) {
#pragma unroll
        for (int i = 0; i < QSTR; ++i) red[wv][i] = acc[i];
    }
    __syncthreads();
    if (threadIdx.x < QSTR) {
        Q[(size_t)(e * NJ + j) * QSTR + threadIdx.x] =
            red[0][threadIdx.x] + red[1][threadIdx.x] + red[2][threadIdx.x] + red[3][threadIdx.x];
    }
}

// ---------------------------------------------------------------------------
// Kernel B: per-batch joints — barrier-free (shfl chain, verified R4) + fused
// extra-joint evaluation from Q: extra[b,e] = Σ_j A_j·u[e,j] + Qw[e,j]·A_j[:,3] + t
// where u_k = beta0*( s·Qsmpl + (1-s)·Qsmil + Σ_l beta_l·Qsd ).
// One wave per batch; lanes 0..23 own joints; inactive lanes contribute zeros.
// ---------------------------------------------------------------------------
__global__ __launch_bounds__(64) void joints_kernel(
    const float* __restrict__ betas,
    const float* __restrict__ body_pose,
    const float* __restrict__ glob_or,
    const float* __restrict__ transl,
    const float* __restrict__ msc,
    const float* __restrict__ jtjs,
    const float* __restrict__ Q,
    float* __restrict__ wsA,
    float* __restrict__ out)
{
    const int b = blockIdx.x;
    const int j = threadIdx.x;          // 0..63, joints on 0..23
    const bool act = j < NJ;
    const float s = msc[0];

    const float beta0 = betas[b * (NBD + 1)];   // uniform → s_load

    float sJ0 = 0.f, sJ1 = 0.f, sJ2 = 0.f;
    float M[12];
#pragma unroll
    for (int k = 0; k < 12; ++k) M[k] = 0.f;

    if (act) {
        float a0 = jtjs[j * 33 + 0];
        float a1 = jtjs[j * 33 + 1];
        float a2 = jtjs[j * 33 + 2];
#pragma unroll
        for (int l = 0; l < NBD; ++l) {
            const float bl = betas[b * (NBD + 1) + 1 + l];   // uniform
            a0 = fmaf(bl, jtjs[j * 33 + 3 + 0 * 10 + l], a0);
            a1 = fmaf(bl, jtjs[j * 33 + 3 + 1 * 10 + l], a1);
            a2 = fmaf(bl, jtjs[j * 33 + 3 + 2 * 10 + l], a2);
        }
        sJ0 = a0 * beta0; sJ1 = a1 * beta0; sJ2 = a2 * beta0;

        float rx, ry, rz;
        if (j == 0) {
            rx = glob_or[b * 3 + 0]; ry = glob_or[b * 3 + 1]; rz = glob_or[b * 3 + 2];
        } else {
            rx = body_pose[b * 69 + (j - 1) * 3 + 0];
            ry = body_pose[b * 69 + (j - 1) * 3 + 1];
            rz = body_pose[b * 69 + (j - 1) * 3 + 2];
        }
        float ex = rx + 1e-8f, ey = ry + 1e-8f, ez = rz + 1e-8f;
        float ang = sqrtf(ex * ex + ey * ey + ez * ez);
        float inv = 1.f / ang;
        float ax = rx * inv, ay = ry * inv, az = rz * inv;
        float c = cosf(ang), sn = sinf(ang), t = 1.f - c;
        M[0]  = 1.f + t * (-(ay * ay + az * az));
        M[1]  = -sn * az + t * (ax * ay);
        M[2]  =  sn * ay + t * (ax * az);
        M[4]  =  sn * az + t * (ax * ay);
        M[5]  = 1.f + t * (-(ax * ax + az * az));
        M[6]  = -sn * ax + t * (ay * az);
        M[8]  = -sn * ay + t * (ax * az);
        M[9]  =  sn * ax + t * (ay * az);
        M[10] = 1.f + t * (-(ax * ax + ay * ay));
    }

    const int p = act ? c_par[j] : 0;
    const int psel = (p >= 0) ? p : 0;
    const int lvl = act ? c_lvl[j] : 0;

    // rel_joints: subtract parent's J
    {
        float pj0 = __shfl(sJ0, psel);
        float pj1 = __shfl(sJ1, psel);
        float pj2 = __shfl(sJ2, psel);
        if (act) {
            M[3]  = sJ0 - ((p >= 0) ? pj0 : 0.f);
            M[7]  = sJ1 - ((p >= 0) ? pj1 : 0.f);
            M[11] = sJ2 - ((p >= 0) ? pj2 : 0.f);
        }
    }

    // chain compose, level-parallel via shfl
    float C[12];
#pragma unroll
    for (int k = 0; k < 12; ++k) C[k] = M[k];
#pragma unroll
    for (int level = 1; level <= 8; ++level) {
        float P[12];
#pragma unroll
        for (int k = 0; k < 12; ++k) P[k] = __shfl(C[k], psel);
        if (act && lvl == level) {
#pragma unroll
            for (int r = 0; r < 3; ++r) {
#pragma unroll
                for (int col = 0; col < 4; ++col) {
                    float acc = (col == 3) ? P[r * 4 + 3] : 0.f;
#pragma unroll
                    for (int q = 0; q < 3; ++q)
                        acc = fmaf(P[r * 4 + q], M[q * 4 + col], acc);
                    C[r * 4 + col] = acc;
                }
            }
        }
    }

    // A = C with corrected translation column (zeros on inactive lanes)
    const float c0 = C[3], c1 = C[7], c2 = C[11];
    const float A3  = c0 - (C[0] * sJ0 + C[1] * sJ1 + C[2]  * sJ2);
    const float A7  = c1 - (C[4] * sJ0 + C[5] * sJ1 + C[6]  * sJ2);
    const float A11 = c2 - (C[8] * sJ0 + C[9] * sJ1 + C[10] * sJ2);

    const float tx = transl[b * 3 + 0], ty = transl[b * 3 + 1], tz = transl[b * 3 + 2];

    if (act) {
        float* Aout = wsA + ((size_t)b * NJ + j) * 12;
        Aout[0] = C[0]; Aout[1] = C[1]; Aout[2]  = C[2];  Aout[3]  = A3;
        Aout[4] = C[4]; Aout[5] = C[5]; Aout[6]  = C[6];  Aout[7]  = A7;
        Aout[8] = C[8]; Aout[9] = C[9]; Aout[10] = C[10]; Aout[11] = A11;

        const size_t o = ((size_t)b * NOUT + NV + j) * 3;
        out[o + 0] = c0 + tx; out[o + 1] = c1 + ty; out[o + 2] = c2 + tz;
    }

    // ---- fused extra joints ----
    float ex[27];
#pragma unroll
    for (int e = 0; e < NEXTRA; ++e) {
        float u0 = 0.f, u1 = 0.f, u2 = 0.f, qw = 0.f;
        if (act) {
            const float* q = Q + (size_t)(e * NJ + j) * QSTR;
            u0 = s * q[0] + (1.f - s) * q[3];
            u1 = s * q[1] + (1.f - s) * q[4];
            u2 = s * q[2] + (1.f - s) * q[5];
#pragma unroll
            for (int l = 0; l < NBD; ++l) {
                const float bl = betas[b * (NBD + 1) + 1 + l];   // uniform
                u0 = fmaf(bl, q[6 + 0 * 10 + l], u0);
                u1 = fmaf(bl, q[6 + 1 * 10 + l], u1);
                u2 = fmaf(bl, q[6 + 2 * 10 + l], u2);
            }
            u0 *= beta0; u1 *= beta0; u2 *= beta0;
            qw = q[36];
        }
        ex[e * 3 + 0] = C[0] * u0 + C[1] * u1 + C[2]  * u2 + A3  * qw;
        ex[e * 3 + 1] = C[4] * u0 + C[5] * u1 + C[6]  * u2 + A7  * qw;
        ex[e * 3 + 2] = C[8] * u0 + C[9] * u1 + C[10] * u2 + A11 * qw;
    }
    // all-lane butterfly (inactive lanes contribute exact zeros)
#pragma unroll
    for (int i = 0; i < 27; ++i) {
        float x = ex[i];
        for (int off = 32; off; off >>= 1) x += __shfl_xor(x, off, 64);
        ex[i] = x;
    }
    if (j == 0) {
        float* dst = out + ((size_t)b * NOUT + NV + NJ) * 3;
#pragma unroll
        for (int e = 0; e < NEXTRA; ++e) {
            dst[e * 3 + 0] = ex[e * 3 + 0] + tx;
            dst[e * 3 + 1] = ex[e * 3 + 1] + ty;
            dst[e * 3 + 2] = ex[e * 3 + 2] + tz;
        }
    }
}

// ---------------------------------------------------------------------------
// Kernel C: pure LBS skinning. grid (27, BATCH/BPB), block 256.
// A[4 batches] staged in LDS (4.6 KB) → broadcast ds_reads. Batch loop not
// unrolled (R2 lesson: unroll → scratch spill).
// ---------------------------------------------------------------------------
__global__ __launch_bounds__(256, 4) void lbs_kernel(
    const float* __restrict__ betas,
    const float* __restrict__ transl,
    const float* __restrict__ msc,
    const float* __restrict__ smpl_t,
    const float* __restrict__ smil_t,
    const float* __restrict__ sdirs,
    const float* __restrict__ lbsw,
    const float* __restrict__ wsA,
    float* __restrict__ out)
{
    __shared__ float sA[BPB * NJ * 12];   // 1152 floats

    const int tid = threadIdx.x;
    const int v = blockIdx.x * 256 + tid;
    const bool valid = v < NV;
    const int vc = valid ? v : NV - 1;
    const int b0 = blockIdx.y * BPB;
    const float s = msc[0];

    for (int i = tid; i < BPB * NJ * 12; i += 256)
        sA[i] = wsA[(size_t)b0 * NJ * 12 + i];

    float vt[3];
#pragma unroll
    for (int k = 0; k < 3; ++k)
        vt[k] = s * smpl_t[vc * 3 + k] + (1.f - s) * smil_t[vc * 3 + k];

    float sd[30];
    {
        const float2* sd2 = (const float2*)(sdirs + (size_t)vc * 30);
#pragma unroll
        for (int i = 0; i < 15; ++i) { float2 x = sd2[i]; sd[2 * i] = x.x; sd[2 * i + 1] = x.y; }
    }
    float w[NJ];
    {
        const float4* w4 = (const float4*)(lbsw + (size_t)vc * NJ);
#pragma unroll
        for (int i = 0; i < 6; ++i) {
            float4 x = w4[i];
            w[4 * i] = x.x; w[4 * i + 1] = x.y; w[4 * i + 2] = x.z; w[4 * i + 3] = x.w;
        }
    }

    __syncthreads();

#pragma unroll 1
    for (int bb = 0; bb < BPB; ++bb) {
        const int b = b0 + bb;
        const float* __restrict__ Bb = betas + b * (NBD + 1);   // uniform → s_load
        const float* Ab = sA + bb * NJ * 12;

        float vs[3];
#pragma unroll
        for (int k = 0; k < 3; ++k) {
            float a = vt[k];
#pragma unroll
            for (int l = 0; l < NBD; ++l) a = fmaf(Bb[1 + l], sd[k * 10 + l], a);
            vs[k] = a * Bb[0];
        }

        float T[12];
#pragma unroll
        for (int k = 0; k < 12; ++k) T[k] = 0.f;
#pragma unroll
        for (int jj = 0; jj < NJ; ++jj) {
            const float ww = w[jj];
#pragma unroll
            for (int k = 0; k < 12; ++k) T[k] = fmaf(ww, Ab[jj * 12 + k], T[k]);
        }

        if (valid) {
            const float tx = transl[b * 3 + 0], ty = transl[b * 3 + 1], tz = transl[b * 3 + 2];
            const size_t o = ((size_t)b * NOUT + v) * 3;
            out[o + 0] = fmaf(T[0], vs[0], fmaf(T[1], vs[1], fmaf(T[2],  vs[2], T[3])))  + tx;
            out[o + 1] = fmaf(T[4], vs[0], fmaf(T[5], vs[1], fmaf(T[6],  vs[2], T[7])))  + ty;
            out[o + 2] = fmaf(T[8], vs[0], fmaf(T[9], vs[1], fmaf(T[10], vs[2], T[11]))) + tz;
        }
    }
}

// ---------------------------------------------------------------------------
extern "C" void kernel_launch(void* const* d_in, const int* in_sizes, int n_in,
                              void* d_out, int out_size, void* d_ws, size_t ws_size,
                              hipStream_t stream) {
    const float* betas     = (const float*)d_in[0];
    const float* body_pose = (const float*)d_in[1];
    const float* glob_or   = (const float*)d_in[2];
    const float* transl    = (const float*)d_in[3];
    const float* msc       = (const float*)d_in[4];
    const float* smpl_t    = (const float*)d_in[5];
    const float* smil_t    = (const float*)d_in[6];
    const float* sdirs     = (const float*)d_in[7];
    const float* jreg      = (const float*)d_in[8];
    const float* lbsw      = (const float*)d_in[9];
    const float* jre       = (const float*)d_in[10];

    float* out  = (float*)d_out;
    float* ws   = (float*)d_ws;
    float* jtjs = ws;                            // 24*33 = 792 floats
    float* wsA  = ws + 792;                      // 512*24*12 = 147456 floats
    float* Q    = wsA + (size_t)BATCH * NJ * 12; // 216*37 = 7992 floats

    hipMemsetAsync(jtjs, 0, NJ * 33 * sizeof(float), stream);

    dim3 gA(VBLK, NJ);
    precompute_kernel<<<gA, 256, 0, stream>>>(jreg, smpl_t, smil_t, sdirs, msc, jtjs);

    dim3 gQ(NEXTRA, NJ);
    q_kernel<<<gQ, 256, 0, stream>>>(jre, lbsw, smpl_t, smil_t, sdirs, Q);

    joints_kernel<<<BATCH, 64, 0, stream>>>(betas, body_pose, glob_or, transl, msc,
                                            jtjs, Q, wsA, out);

    dim3 gC(VBLK, BATCH / BPB);
    lbs_kernel<<<gC, 256, 0, stream>>>(betas, transl, msc, smpl_t, smil_t, sdirs,
                                       lbsw, wsA, out);
}

// Round 6
// 189.270 us; speedup vs baseline: 3.5188x; 2.9972x over previous
//
#include <hip/hip_runtime.h>

// SMPL forward: B=512, V=6890, NB=10, NJ=24, 9 extra joints. Output fp32 (B, 6923, 3).
// R6: memset → precompute(jtjs) → wt(transpose lbsw) → q(chunked, coalesced, atomic)
//     → joints(A + posed + extra via Q algebra) → lbs (BPB=1, spill-proof).

#define BATCH 512
#define NV 6890
#define NBD 10
#define NJ 24
#define NEXTRA 9
#define NOUT (NV + NJ + NEXTRA)   // 6923
#define VBLK ((NV + 255) / 256)   // 27
#define QSTR 37                   // Q row: smpl[3], smil[3], sd[30], w[1]
#define QCH ((NV + 3) / 4)        // 1723 — V-chunk in q_kernel

__constant__ int c_par[NJ] = {-1,0,0,0,1,2,3,4,5,6,7,8,9,9,9,12,13,14,16,17,18,19,20,21};
__constant__ int c_lvl[NJ] = { 0,1,1,1,2,2,2,3,3,3,4,4,4, 4, 4, 5, 5, 5, 6, 6, 7, 7, 8, 8};

// ---------------------------------------------------------------------------
// Kernel A: batch-independent joint-regressor precompute (verified).
// jtjs[j][0:3] = Jreg@v_template ; jtjs[j][3+k*10+l] = Jreg@shapedirs
// ---------------------------------------------------------------------------
__global__ __launch_bounds__(256) void precompute_kernel(
    const float* __restrict__ jreg,
    const float* __restrict__ smpl_t,
    const float* __restrict__ smil_t,
    const float* __restrict__ sdirs,
    const float* __restrict__ msc,
    float* __restrict__ jtjs)
{
    const int j = blockIdx.y;
    const int v = blockIdx.x * 256 + threadIdx.x;
    const float s = msc[0];

    float acc[33];
#pragma unroll
    for (int i = 0; i < 33; ++i) acc[i] = 0.f;

    if (v < NV) {
        const float w = jreg[j * NV + v];
#pragma unroll
        for (int k = 0; k < 3; ++k) {
            float vt = s * smpl_t[v * 3 + k] + (1.f - s) * smil_t[v * 3 + k];
            acc[k] = w * vt;
        }
        const float2* sd2 = (const float2*)(sdirs + (size_t)v * 30);
#pragma unroll
        for (int i = 0; i < 15; ++i) {
            float2 x = sd2[i];
            acc[3 + 2 * i]     = w * x.x;
            acc[3 + 2 * i + 1] = w * x.y;
        }
    }

#pragma unroll
    for (int i = 0; i < 33; ++i) {
        float x = acc[i];
        for (int off = 32; off; off >>= 1) x += __shfl_xor(x, off, 64);
        acc[i] = x;
    }

    __shared__ float red[4][33];
    const int lane = threadIdx.x & 63, wv = threadIdx.x >> 6;
    if (lane == 0) {
#pragma unroll
        for (int i = 0; i < 33; ++i) red[wv][i] = acc[i];
    }
    __syncthreads();
    if (threadIdx.x < 33) {
        float sum = red[0][threadIdx.x] + red[1][threadIdx.x]
                  + red[2][threadIdx.x] + red[3][threadIdx.x];
        atomicAdd(&jtjs[j * 33 + threadIdx.x], sum);
    }
}

// ---------------------------------------------------------------------------
// Kernel A1: transpose lbs weights → wT[j][v] (coalesced q_kernel reads).
// ---------------------------------------------------------------------------
__global__ __launch_bounds__(256) void wt_kernel(
    const float* __restrict__ lbsw,
    float* __restrict__ wT)
{
    const int v = blockIdx.x * 256 + threadIdx.x;
    if (v < NV) {
        const float4* w4 = (const float4*)(lbsw + (size_t)v * NJ);
#pragma unroll
        for (int i = 0; i < 6; ++i) {
            float4 x = w4[i];
            wT[(4 * i + 0) * NV + v] = x.x;
            wT[(4 * i + 1) * NV + v] = x.y;
            wT[(4 * i + 2) * NV + v] = x.z;
            wT[(4 * i + 3) * NV + v] = x.w;
        }
    }
}

// ---------------------------------------------------------------------------
// Kernel A2: extra-joint regressor precompute, chunked + coalesced.
// Q[(e*NJ+j)*37 + m]: m=0..2 Σ jre·w·smpl ; 3..5 Σ jre·w·smil ;
//                     6+k*10+l Σ jre·w·sd[k,l] ; 36 Σ jre·w.
// grid (NEXTRA, NJ, 4 V-chunks) = 864 blocks; atomicAdd partials into zeroed Q.
// ---------------------------------------------------------------------------
__global__ __launch_bounds__(256) void q_kernel(
    const float* __restrict__ jre,
    const float* __restrict__ wT,
    const float* __restrict__ smpl_t,
    const float* __restrict__ smil_t,
    const float* __restrict__ sdirs,
    float* __restrict__ Q)
{
    const int e = blockIdx.x;
    const int j = blockIdx.y;
    const int v0 = blockIdx.z * QCH;
    const int v1 = min(NV, v0 + QCH);

    float acc[QSTR];
#pragma unroll
    for (int i = 0; i < QSTR; ++i) acc[i] = 0.f;

    for (int v = v0 + threadIdx.x; v < v1; v += 256) {
        const float jw = jre[e * NV + v] * wT[j * NV + v];   // both coalesced
        acc[36] += jw;
#pragma unroll
        for (int k = 0; k < 3; ++k) {
            acc[k]     = fmaf(jw, smpl_t[v * 3 + k], acc[k]);
            acc[3 + k] = fmaf(jw, smil_t[v * 3 + k], acc[3 + k]);
        }
        const float2* sd2 = (const float2*)(sdirs + (size_t)v * 30);
#pragma unroll
        for (int i = 0; i < 15; ++i) {
            float2 x = sd2[i];
            acc[6 + 2 * i]     = fmaf(jw, x.x, acc[6 + 2 * i]);
            acc[6 + 2 * i + 1] = fmaf(jw, x.y, acc[6 + 2 * i + 1]);
        }
    }

#pragma unroll
    for (int i = 0; i < QSTR; ++i) {
        float x = acc[i];
        for (int off = 32; off; off >>= 1) x += __shfl_xor(x, off, 64);
        acc[i] = x;
    }
    __shared__ float red[4][QSTR];
    const int lane = threadIdx.x & 63, wv = threadIdx.x >> 6;
    if (lane == 0) {
#pragma unroll
        for (int i = 0; i < QSTR; ++i) red[wv][i] = acc[i];
    }
    __syncthreads();
    if (threadIdx.x < QSTR) {
        atomicAdd(&Q[(size_t)(e * NJ + j) * QSTR + threadIdx.x],
                  red[0][threadIdx.x] + red[1][threadIdx.x]
                + red[2][threadIdx.x] + red[3][threadIdx.x]);
    }
}

// ---------------------------------------------------------------------------
// Kernel B: per-batch joints — shfl chain + fused extra joints via Q (verified R5).
// ---------------------------------------------------------------------------
__global__ __launch_bounds__(64) void joints_kernel(
    const float* __restrict__ betas,
    const float* __restrict__ body_pose,
    const float* __restrict__ glob_or,
    const float* __restrict__ transl,
    const float* __restrict__ msc,
    const float* __restrict__ jtjs,
    const float* __restrict__ Q,
    float* __restrict__ wsA,
    float* __restrict__ out)
{
    const int b = blockIdx.x;
    const int j = threadIdx.x;
    const bool act = j < NJ;
    const float s = msc[0];

    const float beta0 = betas[b * (NBD + 1)];

    float sJ0 = 0.f, sJ1 = 0.f, sJ2 = 0.f;
    float M[12];
#pragma unroll
    for (int k = 0; k < 12; ++k) M[k] = 0.f;

    if (act) {
        float a0 = jtjs[j * 33 + 0];
        float a1 = jtjs[j * 33 + 1];
        float a2 = jtjs[j * 33 + 2];
#pragma unroll
        for (int l = 0; l < NBD; ++l) {
            const float bl = betas[b * (NBD + 1) + 1 + l];
            a0 = fmaf(bl, jtjs[j * 33 + 3 + 0 * 10 + l], a0);
            a1 = fmaf(bl, jtjs[j * 33 + 3 + 1 * 10 + l], a1);
            a2 = fmaf(bl, jtjs[j * 33 + 3 + 2 * 10 + l], a2);
        }
        sJ0 = a0 * beta0; sJ1 = a1 * beta0; sJ2 = a2 * beta0;

        float rx, ry, rz;
        if (j == 0) {
            rx = glob_or[b * 3 + 0]; ry = glob_or[b * 3 + 1]; rz = glob_or[b * 3 + 2];
        } else {
            rx = body_pose[b * 69 + (j - 1) * 3 + 0];
            ry = body_pose[b * 69 + (j - 1) * 3 + 1];
            rz = body_pose[b * 69 + (j - 1) * 3 + 2];
        }
        float ex = rx + 1e-8f, ey = ry + 1e-8f, ez = rz + 1e-8f;
        float ang = sqrtf(ex * ex + ey * ey + ez * ez);
        float inv = 1.f / ang;
        float ax = rx * inv, ay = ry * inv, az = rz * inv;
        float c = cosf(ang), sn = sinf(ang), t = 1.f - c;
        M[0]  = 1.f + t * (-(ay * ay + az * az));
        M[1]  = -sn * az + t * (ax * ay);
        M[2]  =  sn * ay + t * (ax * az);
        M[4]  =  sn * az + t * (ax * ay);
        M[5]  = 1.f + t * (-(ax * ax + az * az));
        M[6]  = -sn * ax + t * (ay * az);
        M[8]  = -sn * ay + t * (ax * az);
        M[9]  =  sn * ax + t * (ay * az);
        M[10] = 1.f + t * (-(ax * ax + ay * ay));
    }

    const int p = act ? c_par[j] : 0;
    const int psel = (p >= 0) ? p : 0;
    const int lvl = act ? c_lvl[j] : 0;

    {
        float pj0 = __shfl(sJ0, psel);
        float pj1 = __shfl(sJ1, psel);
        float pj2 = __shfl(sJ2, psel);
        if (act) {
            M[3]  = sJ0 - ((p >= 0) ? pj0 : 0.f);
            M[7]  = sJ1 - ((p >= 0) ? pj1 : 0.f);
            M[11] = sJ2 - ((p >= 0) ? pj2 : 0.f);
        }
    }

    float C[12];
#pragma unroll
    for (int k = 0; k < 12; ++k) C[k] = M[k];
#pragma unroll
    for (int level = 1; level <= 8; ++level) {
        float P[12];
#pragma unroll
        for (int k = 0; k < 12; ++k) P[k] = __shfl(C[k], psel);
        if (act && lvl == level) {
#pragma unroll
            for (int r = 0; r < 3; ++r) {
#pragma unroll
                for (int col = 0; col < 4; ++col) {
                    float acc = (col == 3) ? P[r * 4 + 3] : 0.f;
#pragma unroll
                    for (int q = 0; q < 3; ++q)
                        acc = fmaf(P[r * 4 + q], M[q * 4 + col], acc);
                    C[r * 4 + col] = acc;
                }
            }
        }
    }

    const float c0 = C[3], c1 = C[7], c2 = C[11];
    const float A3  = c0 - (C[0] * sJ0 + C[1] * sJ1 + C[2]  * sJ2);
    const float A7  = c1 - (C[4] * sJ0 + C[5] * sJ1 + C[6]  * sJ2);
    const float A11 = c2 - (C[8] * sJ0 + C[9] * sJ1 + C[10] * sJ2);

    const float tx = transl[b * 3 + 0], ty = transl[b * 3 + 1], tz = transl[b * 3 + 2];

    if (act) {
        float* Aout = wsA + ((size_t)b * NJ + j) * 12;
        Aout[0] = C[0]; Aout[1] = C[1]; Aout[2]  = C[2];  Aout[3]  = A3;
        Aout[4] = C[4]; Aout[5] = C[5]; Aout[6]  = C[6];  Aout[7]  = A7;
        Aout[8] = C[8]; Aout[9] = C[9]; Aout[10] = C[10]; Aout[11] = A11;

        const size_t o = ((size_t)b * NOUT + NV + j) * 3;
        out[o + 0] = c0 + tx; out[o + 1] = c1 + ty; out[o + 2] = c2 + tz;
    }

    // fused extra joints
    float ex[27];
#pragma unroll
    for (int e = 0; e < NEXTRA; ++e) {
        float u0 = 0.f, u1 = 0.f, u2 = 0.f, qw = 0.f;
        if (act) {
            const float* q = Q + (size_t)(e * NJ + j) * QSTR;
            u0 = s * q[0] + (1.f - s) * q[3];
            u1 = s * q[1] + (1.f - s) * q[4];
            u2 = s * q[2] + (1.f - s) * q[5];
#pragma unroll
            for (int l = 0; l < NBD; ++l) {
                const float bl = betas[b * (NBD + 1) + 1 + l];
                u0 = fmaf(bl, q[6 + 0 * 10 + l], u0);
                u1 = fmaf(bl, q[6 + 1 * 10 + l], u1);
                u2 = fmaf(bl, q[6 + 2 * 10 + l], u2);
            }
            u0 *= beta0; u1 *= beta0; u2 *= beta0;
            qw = q[36];
        }
        ex[e * 3 + 0] = C[0] * u0 + C[1] * u1 + C[2]  * u2 + A3  * qw;
        ex[e * 3 + 1] = C[4] * u0 + C[5] * u1 + C[6]  * u2 + A7  * qw;
        ex[e * 3 + 2] = C[8] * u0 + C[9] * u1 + C[10] * u2 + A11 * qw;
    }
#pragma unroll
    for (int i = 0; i < 27; ++i) {
        float x = ex[i];
        for (int off = 32; off; off >>= 1) x += __shfl_xor(x, off, 64);
        ex[i] = x;
    }
    if (j == 0) {
        float* dst = out + ((size_t)b * NOUT + NV + NJ) * 3;
#pragma unroll
        for (int e = 0; e < NEXTRA; ++e) {
            dst[e * 3 + 0] = ex[e * 3 + 0] + tx;
            dst[e * 3 + 1] = ex[e * 3 + 1] + ty;
            dst[e * 3 + 2] = ex[e * 3 + 2] + tz;
        }
    }
}

// ---------------------------------------------------------------------------
// Kernel C: LBS skinning, BPB=1 — one (vertex,batch) per thread, grid (27,512).
// No state survives an iteration → no long-liveness arrays → no spill.
// A/betas uniform per block → s_load; (256,8) caps VGPR at 64 → 8 waves/SIMD
// so chunked lgkmcnt waits hide via TLP. Per-vertex data re-read per batch is
// L2-hot (1.7 MB working set << 4 MB/XCD).
// ---------------------------------------------------------------------------
__global__ __launch_bounds__(256, 8) void lbs_kernel(
    const float* __restrict__ betas,
    const float* __restrict__ transl,
    const float* __restrict__ msc,
    const float* __restrict__ smpl_t,
    const float* __restrict__ smil_t,
    const float* __restrict__ sdirs,
    const float* __restrict__ lbsw,
    const float* __restrict__ wsA,
    float* __restrict__ out)
{
    const int v = blockIdx.x * 256 + threadIdx.x;
    if (v >= NV) return;                       // no barriers/shfl below — safe
    const int b = blockIdx.y;
    const float s = msc[0];

    const float* __restrict__ Bb = betas + b * (NBD + 1);     // uniform → s_load
    const float* __restrict__ Ab = wsA + (size_t)b * NJ * 12; // uniform → s_load

    // v_shaped (sd transients die immediately)
    float vs[3];
    {
        const float2* sd2 = (const float2*)(sdirs + (size_t)v * 30);
#pragma unroll
        for (int k = 0; k < 3; ++k) {
            float a = s * smpl_t[v * 3 + k] + (1.f - s) * smil_t[v * 3 + k];
#pragma unroll
            for (int l = 0; l < NBD; ++l) {
                const int idx = k * 10 + l;
                const float sdv = (idx & 1) ? sd2[idx >> 1].y : sd2[idx >> 1].x;
                a = fmaf(Bb[1 + l], sdv, a);
            }
            vs[k] = a * Bb[0];
        }
    }

    // T = sum_j w_j * A_j
    float T[12];
#pragma unroll
    for (int k = 0; k < 12; ++k) T[k] = 0.f;
    const float4* w4 = (const float4*)(lbsw + (size_t)v * NJ);
#pragma unroll
    for (int i = 0; i < 6; ++i) {
        const float4 x = w4[i];
        const float wv[4] = {x.x, x.y, x.z, x.w};
#pragma unroll
        for (int u = 0; u < 4; ++u) {
            const int jj = 4 * i + u;
#pragma unroll
            for (int k = 0; k < 12; ++k) T[k] = fmaf(wv[u], Ab[jj * 12 + k], T[k]);
        }
    }

    const float tx = transl[b * 3 + 0], ty = transl[b * 3 + 1], tz = transl[b * 3 + 2];
    const size_t o = ((size_t)b * NOUT + v) * 3;
    out[o + 0] = fmaf(T[0], vs[0], fmaf(T[1], vs[1], fmaf(T[2],  vs[2], T[3])))  + tx;
    out[o + 1] = fmaf(T[4], vs[0], fmaf(T[5], vs[1], fmaf(T[6],  vs[2], T[7])))  + ty;
    out[o + 2] = fmaf(T[8], vs[0], fmaf(T[9], vs[1], fmaf(T[10], vs[2], T[11]))) + tz;
}

// ---------------------------------------------------------------------------
extern "C" void kernel_launch(void* const* d_in, const int* in_sizes, int n_in,
                              void* d_out, int out_size, void* d_ws, size_t ws_size,
                              hipStream_t stream) {
    const float* betas     = (const float*)d_in[0];
    const float* body_pose = (const float*)d_in[1];
    const float* glob_or   = (const float*)d_in[2];
    const float* transl    = (const float*)d_in[3];
    const float* msc       = (const float*)d_in[4];
    const float* smpl_t    = (const float*)d_in[5];
    const float* smil_t    = (const float*)d_in[6];
    const float* sdirs     = (const float*)d_in[7];
    const float* jreg      = (const float*)d_in[8];
    const float* lbsw      = (const float*)d_in[9];
    const float* jre       = (const float*)d_in[10];

    float* out  = (float*)d_out;
    float* ws   = (float*)d_ws;
    float* jtjs = ws;                              // 24*33 = 792
    float* Q    = ws + 792;                        // 216*37 = 7992
    float* wsA  = Q + 7992;                        // 512*24*12 = 147456
    float* wT   = wsA + (size_t)BATCH * NJ * 12;   // 24*6890 = 165360

    // zero both atomic accumulators (jtjs + Q are contiguous)
    hipMemsetAsync(jtjs, 0, (792 + 7992) * sizeof(float), stream);

    dim3 gA(VBLK, NJ);
    precompute_kernel<<<gA, 256, 0, stream>>>(jreg, smpl_t, smil_t, sdirs, msc, jtjs);

    wt_kernel<<<VBLK, 256, 0, stream>>>(lbsw, wT);

    dim3 gQ(NEXTRA, NJ, 4);
    q_kernel<<<gQ, 256, 0, stream>>>(jre, wT, smpl_t, smil_t, sdirs, Q);

    joints_kernel<<<BATCH, 64, 0, stream>>>(betas, body_pose, glob_or, transl, msc,
                                            jtjs, Q, wsA, out);

    dim3 gC(VBLK, BATCH);
    lbs_kernel<<<gC, 256, 0, stream>>>(betas, transl, msc, smpl_t, smil_t, sdirs,
                                       lbsw, wsA, out);
}